// Round 3
// baseline (397.302 us; speedup 1.0000x reference)
//
#include <hip/hip_runtime.h>
#include <hip/hip_bf16.h>

typedef __attribute__((ext_vector_type(8))) _Float16 half8;
typedef __attribute__((ext_vector_type(4))) float f32x4;

#define LOG2E 1.4426950408889634f

// ---------------- kernel 1: f32 -> fp16 cast (8 elems/thread) ----------------
__global__ __launch_bounds__(256) void cvt_h_kernel(const float* __restrict__ x,
                                                    _Float16* __restrict__ y) {
  size_t i = (size_t)blockIdx.x * 256 + threadIdx.x;   // 524288 threads, 8 elems each
  const f32x4* p = (const f32x4*)x + i * 2;
  f32x4 a = p[0], b = p[1];
  half8 o;
  o[0] = (_Float16)a[0]; o[1] = (_Float16)a[1];
  o[2] = (_Float16)a[2]; o[3] = (_Float16)a[3];
  o[4] = (_Float16)b[0]; o[5] = (_Float16)b[1];
  o[6] = (_Float16)b[2]; o[7] = (_Float16)b[3];
  ((half8*)y)[i] = o;
}

// ------------- kernel 2: W [512k][512n] f32 -> Wt [512n][512k] fp16 ----------
__global__ __launch_bounds__(256) void wtrans_kernel(const float* __restrict__ W,
                                                     _Float16* __restrict__ Wt) {
  __shared__ float tile[32][33];
  int k0 = blockIdx.x * 32, n0 = blockIdx.y * 32;
  int c = threadIdx.x & 31, r0 = threadIdx.x >> 5;
  #pragma unroll
  for (int rr = 0; rr < 32; rr += 8)
    tile[r0 + rr][c] = W[(size_t)(k0 + r0 + rr) * 512 + n0 + c];
  __syncthreads();
  #pragma unroll
  for (int rr = 0; rr < 32; rr += 8)
    Wt[(size_t)(n0 + r0 + rr) * 512 + k0 + c] = (_Float16)tile[c][r0 + rr];
}

// ---------------- kernel 3: projection GEMM (fp16 MFMA 16x16x32) -------------
// X: [8192][512] f16. Wt: [512n][512k] f16. Tile 128M x 64N, 4 waves.
// vmode==0: out [B,H,S,64];  vmode==1: out Vt [B,H,64,S] (LDS transpose epilogue)
__global__ __launch_bounds__(256) void proj_kernel(const _Float16* __restrict__ X,
                                                   const _Float16* __restrict__ Wt,
                                                   _Float16* __restrict__ outp,
                                                   int vmode) {
  __shared__ __align__(16) char lt_all[4 * 64 * 144];
  const int wave = threadIdx.x >> 6, lane = threadIdx.x & 63;
  const int g = lane >> 4, li = lane & 15;
  const int m0 = blockIdx.x * 128 + wave * 32;
  const int h = blockIdx.y;                    // n0 = h*64

  f32x4 acc[2][4];
  #pragma unroll
  for (int i = 0; i < 2; ++i)
    #pragma unroll
    for (int j = 0; j < 4; ++j) acc[i][j] = (f32x4){0.f, 0.f, 0.f, 0.f};

  const _Float16* xa = X + (size_t)m0 * 512;
  const _Float16* wb = Wt + (size_t)(h << 6) * 512;

  for (int k0 = 0; k0 < 512; k0 += 32) {
    half8 a[2], bw[4];
    #pragma unroll
    for (int rt = 0; rt < 2; ++rt)
      a[rt] = *(const half8*)(xa + (size_t)(rt * 16 + li) * 512 + k0 + g * 8);
    #pragma unroll
    for (int ct = 0; ct < 4; ++ct)
      bw[ct] = *(const half8*)(wb + (size_t)(ct * 16 + li) * 512 + k0 + g * 8);
    #pragma unroll
    for (int rt = 0; rt < 2; ++rt)
      #pragma unroll
      for (int ct = 0; ct < 4; ++ct)
        acc[rt][ct] = __builtin_amdgcn_mfma_f32_16x16x32_f16(a[rt], bw[ct], acc[rt][ct], 0, 0, 0);
  }

  const int bidx = m0 >> 11, sbase = m0 & 2047;
  if (!vmode) {
    #pragma unroll
    for (int rt = 0; rt < 2; ++rt)
      #pragma unroll
      for (int r = 0; r < 4; ++r) {
        int s = sbase + rt * 16 + g * 4 + r;
        _Float16* orow = outp + ((size_t)((bidx * 8 + h) * 2048 + s) << 6);
        #pragma unroll
        for (int ct = 0; ct < 4; ++ct)
          orow[ct * 16 + li] = (_Float16)acc[rt][ct][r];
      }
  } else {
    // transpose 32s x 64d tile through swizzled LDS, emit Vt rows
    char* lt = lt_all + wave * (64 * 144);
    #pragma unroll
    for (int rt = 0; rt < 2; ++rt)
      #pragma unroll
      for (int ct = 0; ct < 4; ++ct)
        #pragma unroll
        for (int r = 0; r < 4; ++r) {
          int d = ct * 16 + li, sl = rt * 16 + g * 4 + r;
          *(_Float16*)(lt + d * 144 + ((sl * 2) ^ ((d & 7) << 4))) = (_Float16)acc[rt][ct][r];
        }
    __syncthreads();
    int d = lane;  // 0..63
    _Float16* vrow = outp + (size_t)((bidx * 8 + h) * 64 + d) * 2048 + sbase;
    #pragma unroll
    for (int c = 0; c < 4; ++c) {
      half8 vv = *(half8*)(lt + d * 144 + ((c * 16) ^ ((d & 7) << 4)));
      *(half8*)(vrow + c * 8) = vv;
    }
  }
}

// ---------------- kernel 4: fused flash attention + T5 relative bias ---------
// grid (S/128, B*H); block 256 (4 waves x 32 q-rows). KV read direct from L2.
__global__ __launch_bounds__(256) void attn_kernel(const _Float16* __restrict__ Qp,
                                                   const _Float16* __restrict__ Kp,
                                                   const _Float16* __restrict__ Vt,
                                                   const float* __restrict__ kmask,
                                                   const float* __restrict__ rel_emb,
                                                   float* __restrict__ outp) {
  __shared__ float bias_tab[4096];
  __shared__ __align__(16) char pb_all[4 * 4096];
  const int bh = blockIdx.y, b = bh >> 3, h = bh & 7;
  const int wave = threadIdx.x >> 6, lane = threadIdx.x & 63;
  const int g = lane >> 4, li = lane & 15;
  const int qw = blockIdx.x * 128 + wave * 32;

  // T5 bucket bias table for this head; exact integer thresholds (no logf).
  for (int idx = (int)threadIdx.x; idx < 4095; idx += 256) {
    int rel = idx - 2047;
    int ret = rel > 0 ? 16 : 0;
    int rp = rel < 0 ? -rel : rel;
    int bb;
    if (rp < 8) bb = rp;
    else {
      int t = (rp >= 12) + (rp >= 16) + (rp >= 23) + (rp >= 32) +
              (rp >= 46) + (rp >= 64) + (rp >= 91);
      bb = 8 + t;
    }
    bias_tab[idx] = rel_emb[(ret + bb) * 8 + h];
  }
  const float bias_far_neg = rel_emb[15 * 8 + h];   // rel <= -91
  const float bias_far_pos = rel_emb[31 * 8 + h];   // rel >=  91

  const _Float16* Qb = Qp + (size_t)bh * (2048 * 64);
  const _Float16* Kb = Kp + (size_t)bh * (2048 * 64);
  const _Float16* Vb = Vt + (size_t)bh * (64 * 2048);
  const float* mkb = kmask + b * 2048;

  half8 qa[2][2];
  #pragma unroll
  for (int rt = 0; rt < 2; ++rt)
    #pragma unroll
    for (int kc = 0; kc < 2; ++kc)
      qa[rt][kc] = *(const half8*)(Qb + (size_t)(qw + rt * 16 + li) * 64 + kc * 32 + g * 8);

  f32x4 o[2][4];
  float mrow[2][4], lrow[2][4];
  #pragma unroll
  for (int rt = 0; rt < 2; ++rt) {
    #pragma unroll
    for (int ct = 0; ct < 4; ++ct) o[rt][ct] = (f32x4){0.f, 0.f, 0.f, 0.f};
    #pragma unroll
    for (int r = 0; r < 4; ++r) { mrow[rt][r] = -1e30f; lrow[rt][r] = 0.f; }
  }
  char* pb = pb_all + wave * 4096;

  __syncthreads();   // bias table ready

  for (int j0 = 0; j0 < 2048; j0 += 64) {
    // ---- K fragments (direct 16B loads, L2-resident) ----
    half8 kb[4][2];
    #pragma unroll
    for (int jt = 0; jt < 4; ++jt)
      #pragma unroll
      for (int kc = 0; kc < 2; ++kc)
        kb[jt][kc] = *(const half8*)(Kb + (size_t)(j0 + jt * 16 + li) * 64 + kc * 32 + g * 8);
    float mterm[4];
    #pragma unroll
    for (int jt = 0; jt < 4; ++jt)
      mterm[jt] = (1.0f - mkb[j0 + jt * 16 + li]) * -10000.0f;

    // ---- scores = Q K^T ----
    f32x4 sc[2][4];
    #pragma unroll
    for (int rt = 0; rt < 2; ++rt)
      #pragma unroll
      for (int jt = 0; jt < 4; ++jt) {
        f32x4 z = (f32x4){0.f, 0.f, 0.f, 0.f};
        z = __builtin_amdgcn_mfma_f32_16x16x32_f16(qa[rt][0], kb[jt][0], z, 0, 0, 0);
        sc[rt][jt] = __builtin_amdgcn_mfma_f32_16x16x32_f16(qa[rt][1], kb[jt][1], z, 0, 0, 0);
      }

    // ---- bias + mask (wave-uniform far-tile fast path) ----
    #pragma unroll
    for (int rt = 0; rt < 2; ++rt)
      #pragma unroll
      for (int jt = 0; jt < 4; ++jt) {
        int jlo = j0 + jt * 16, qlo = qw + rt * 16;
        if (jlo - (qlo + 15) >= 91) {
          #pragma unroll
          for (int r = 0; r < 4; ++r) sc[rt][jt][r] += bias_far_pos + mterm[jt];
        } else if ((jlo + 15) - qlo <= -91) {
          #pragma unroll
          for (int r = 0; r < 4; ++r) sc[rt][jt][r] += bias_far_neg + mterm[jt];
        } else {
          #pragma unroll
          for (int r = 0; r < 4; ++r)
            sc[rt][jt][r] += bias_tab[(jlo + li) - (qlo + g * 4 + r) + 2047] + mterm[jt];
        }
      }

    // ---- online softmax (16-lane butterfly over columns) ----
    #pragma unroll
    for (int rt = 0; rt < 2; ++rt) {
      float mnew[4], scal[4];
      #pragma unroll
      for (int r = 0; r < 4; ++r) {
        float t = fmaxf(fmaxf(sc[rt][0][r], sc[rt][1][r]), fmaxf(sc[rt][2][r], sc[rt][3][r]));
        t = fmaxf(t, __shfl_xor(t, 1));
        t = fmaxf(t, __shfl_xor(t, 2));
        t = fmaxf(t, __shfl_xor(t, 4));
        t = fmaxf(t, __shfl_xor(t, 8));
        mnew[r] = fmaxf(mrow[rt][r], t);
        scal[r] = exp2f((mrow[rt][r] - mnew[r]) * LOG2E);
        mrow[rt][r] = mnew[r];
      }
      #pragma unroll
      for (int r = 0; r < 4; ++r) {
        float ps = 0.f;
        #pragma unroll
        for (int jt = 0; jt < 4; ++jt) {
          float p = exp2f((sc[rt][jt][r] - mnew[r]) * LOG2E);
          sc[rt][jt][r] = p;
          ps += p;
        }
        lrow[rt][r] = lrow[rt][r] * scal[r] + ps;   // per-lane partial; reduced at end
      }
      #pragma unroll
      for (int ct = 0; ct < 4; ++ct)
        #pragma unroll
        for (int r = 0; r < 4; ++r)
          o[rt][ct][r] *= scal[r];
    }

    // ---- P -> fp16 -> wave-private swizzled LDS (C-layout -> A-layout) ----
    #pragma unroll
    for (int rt = 0; rt < 2; ++rt)
      #pragma unroll
      for (int jt = 0; jt < 4; ++jt)
        #pragma unroll
        for (int r = 0; r < 4; ++r) {
          int row = rt * 16 + g * 4 + r, col = jt * 16 + li;
          *(_Float16*)(pb + row * 128 + ((col * 2) ^ ((row & 7) << 4))) =
              (_Float16)sc[rt][jt][r];
        }
    half8 pa[2][2];
    #pragma unroll
    for (int rt = 0; rt < 2; ++rt)
      #pragma unroll
      for (int jc = 0; jc < 2; ++jc) {
        int row = rt * 16 + li;
        pa[rt][jc] = *(half8*)(pb + row * 128 + (((jc * 32 + g * 8) * 2) ^ ((row & 7) << 4)));
      }

    // ---- O += P V  (V pre-transposed: direct contiguous 16B B-frags) ----
    #pragma unroll
    for (int dct = 0; dct < 4; ++dct) {
      half8 vb0 = *(const half8*)(Vb + (size_t)(dct * 16 + li) * 2048 + j0 + g * 8);
      half8 vb1 = *(const half8*)(Vb + (size_t)(dct * 16 + li) * 2048 + j0 + 32 + g * 8);
      #pragma unroll
      for (int rt = 0; rt < 2; ++rt) {
        o[rt][dct] = __builtin_amdgcn_mfma_f32_16x16x32_f16(pa[rt][0], vb0, o[rt][dct], 0, 0, 0);
        o[rt][dct] = __builtin_amdgcn_mfma_f32_16x16x32_f16(pa[rt][1], vb1, o[rt][dct], 0, 0, 0);
      }
    }
  }

  // ---- epilogue: reduce l, divide, store f32 ----
  #pragma unroll
  for (int rt = 0; rt < 2; ++rt)
    #pragma unroll
    for (int r = 0; r < 4; ++r) {
      float t = lrow[rt][r];
      t += __shfl_xor(t, 1);
      t += __shfl_xor(t, 2);
      t += __shfl_xor(t, 4);
      t += __shfl_xor(t, 8);
      float inv = 1.0f / t;
      int qrow = qw + rt * 16 + g * 4 + r;
      float* orow = outp + ((size_t)b * 2048 + qrow) * 512 + h * 64;
      #pragma unroll
      for (int ct = 0; ct < 4; ++ct)
        orow[ct * 16 + li] = o[rt][ct][r] * inv;
    }
}

extern "C" void kernel_launch(void* const* d_in, const int* in_sizes, int n_in,
                              void* d_out, int out_size, void* d_ws, size_t ws_size,
                              hipStream_t stream) {
  const float* query = (const float*)d_in[0];
  const float* key   = (const float*)d_in[1];
  const float* value = (const float*)d_in[2];
  const float* kmask = (const float*)d_in[3];
  const float* Wq    = (const float*)d_in[4];
  const float* Wk    = (const float*)d_in[5];
  const float* Wv    = (const float*)d_in[6];
  const float* rel   = (const float*)d_in[7];

  char* ws = (char*)d_ws;
  const size_t SZB = 8192ull * 512 * 2;   // one f16 tensor: 8 MiB
  const size_t WB  = 512ull * 512 * 2;
  _Float16* xq  = (_Float16*)(ws);
  _Float16* xk  = (_Float16*)(ws + SZB);
  _Float16* xv  = (_Float16*)(ws + 2 * SZB);
  _Float16* wtq = (_Float16*)(ws + 3 * SZB);
  _Float16* wtk = (_Float16*)(ws + 3 * SZB + WB);
  _Float16* wtv = (_Float16*)(ws + 3 * SZB + 2 * WB);
  _Float16* qp  = (_Float16*)(ws + 3 * SZB + 3 * WB);
  _Float16* kp  = (_Float16*)(ws + 4 * SZB + 3 * WB);
  _Float16* vt  = (_Float16*)(ws + 5 * SZB + 3 * WB);

  cvt_h_kernel<<<dim3(2048), dim3(256), 0, stream>>>(query, xq);
  cvt_h_kernel<<<dim3(2048), dim3(256), 0, stream>>>(key,   xk);
  cvt_h_kernel<<<dim3(2048), dim3(256), 0, stream>>>(value, xv);
  wtrans_kernel<<<dim3(16, 16), dim3(256), 0, stream>>>(Wq, wtq);
  wtrans_kernel<<<dim3(16, 16), dim3(256), 0, stream>>>(Wk, wtk);
  wtrans_kernel<<<dim3(16, 16), dim3(256), 0, stream>>>(Wv, wtv);
  proj_kernel<<<dim3(64, 8), dim3(256), 0, stream>>>(xq, wtq, qp, 0);
  proj_kernel<<<dim3(64, 8), dim3(256), 0, stream>>>(xk, wtk, kp, 0);
  proj_kernel<<<dim3(64, 8), dim3(256), 0, stream>>>(xv, wtv, vt, 1);
  attn_kernel<<<dim3(16, 32), dim3(256), 0, stream>>>(qp, kp, vt, kmask, rel, (float*)d_out);
}

// Round 4
// 310.015 us; speedup vs baseline: 1.2816x; 1.2816x over previous
//
#include <hip/hip_runtime.h>
#include <hip/hip_bf16.h>

typedef __attribute__((ext_vector_type(8))) _Float16 half8;
typedef __attribute__((ext_vector_type(4))) float f32x4;

#define LOG2E 1.4426950408889634f

// ------------- kernel 1: f32 -> fp16 cast, all 3 tensors in one dispatch -----
__global__ __launch_bounds__(256) void cvt_h_kernel(const float* __restrict__ q,
                                                    const float* __restrict__ k,
                                                    const float* __restrict__ v,
                                                    _Float16* __restrict__ xq,
                                                    _Float16* __restrict__ xk,
                                                    _Float16* __restrict__ xv) {
  const int z = blockIdx.y;
  const float* x = z == 0 ? q : z == 1 ? k : v;
  _Float16* y = z == 0 ? xq : z == 1 ? xk : xv;
  size_t i = (size_t)blockIdx.x * 256 + threadIdx.x;   // 8 elems/thread
  const f32x4* p = (const f32x4*)x + i * 2;
  f32x4 a = p[0], b = p[1];
  half8 o;
  o[0] = (_Float16)a[0]; o[1] = (_Float16)a[1];
  o[2] = (_Float16)a[2]; o[3] = (_Float16)a[3];
  o[4] = (_Float16)b[0]; o[5] = (_Float16)b[1];
  o[6] = (_Float16)b[2]; o[7] = (_Float16)b[3];
  ((half8*)y)[i] = o;
}

// ------------- kernel 2: W [512k][512n] f32 -> Wt [512n][512k] fp16 (x3) -----
__global__ __launch_bounds__(256) void wtrans_kernel(const float* __restrict__ Wq,
                                                     const float* __restrict__ Wk,
                                                     const float* __restrict__ Wv,
                                                     _Float16* __restrict__ wtq,
                                                     _Float16* __restrict__ wtk,
                                                     _Float16* __restrict__ wtv) {
  const int z = blockIdx.z;
  const float* W = z == 0 ? Wq : z == 1 ? Wk : Wv;
  _Float16* Wt = z == 0 ? wtq : z == 1 ? wtk : wtv;
  __shared__ float tile[32][33];
  int k0 = blockIdx.x * 32, n0 = blockIdx.y * 32;
  int c = threadIdx.x & 31, r0 = threadIdx.x >> 5;
  #pragma unroll
  for (int rr = 0; rr < 32; rr += 8)
    tile[r0 + rr][c] = W[(size_t)(k0 + r0 + rr) * 512 + n0 + c];
  __syncthreads();
  #pragma unroll
  for (int rr = 0; rr < 32; rr += 8)
    Wt[(size_t)(n0 + r0 + rr) * 512 + k0 + c] = (_Float16)tile[c][r0 + rr];
}

// ---------------- kernel 3: all 3 projection GEMMs in one dispatch -----------
// X: [8192][512] f16. Wt: [512n][512k] f16. Tile 128M x 64N, 4 waves.
// z==0/1: out [B,H,S,64] (Q/K);  z==2: out Vt [B,H,64,S] (LDS transpose)
__global__ __launch_bounds__(256) void proj_kernel(const _Float16* __restrict__ Xq,
                                                   const _Float16* __restrict__ Xk,
                                                   const _Float16* __restrict__ Xv,
                                                   const _Float16* __restrict__ Wtq,
                                                   const _Float16* __restrict__ Wtk,
                                                   const _Float16* __restrict__ Wtv,
                                                   _Float16* __restrict__ Qp,
                                                   _Float16* __restrict__ Kp,
                                                   _Float16* __restrict__ Vt) {
  const int z = blockIdx.z;
  const _Float16* X  = z == 0 ? Xq : z == 1 ? Xk : Xv;
  const _Float16* Wt = z == 0 ? Wtq : z == 1 ? Wtk : Wtv;
  _Float16* outp     = z == 0 ? Qp : z == 1 ? Kp : Vt;

  __shared__ __align__(16) char lt_all[4 * 64 * 144];
  const int wave = threadIdx.x >> 6, lane = threadIdx.x & 63;
  const int g = lane >> 4, li = lane & 15;
  const int m0 = blockIdx.x * 128 + wave * 32;
  const int h = blockIdx.y;                    // n0 = h*64

  f32x4 acc[2][4];
  #pragma unroll
  for (int i = 0; i < 2; ++i)
    #pragma unroll
    for (int j = 0; j < 4; ++j) acc[i][j] = (f32x4){0.f, 0.f, 0.f, 0.f};

  const _Float16* xa = X + (size_t)m0 * 512;
  const _Float16* wb = Wt + (size_t)(h << 6) * 512;

  for (int k0 = 0; k0 < 512; k0 += 32) {
    half8 a[2], bw[4];
    #pragma unroll
    for (int rt = 0; rt < 2; ++rt)
      a[rt] = *(const half8*)(xa + (size_t)(rt * 16 + li) * 512 + k0 + g * 8);
    #pragma unroll
    for (int ct = 0; ct < 4; ++ct)
      bw[ct] = *(const half8*)(wb + (size_t)(ct * 16 + li) * 512 + k0 + g * 8);
    #pragma unroll
    for (int rt = 0; rt < 2; ++rt)
      #pragma unroll
      for (int ct = 0; ct < 4; ++ct)
        acc[rt][ct] = __builtin_amdgcn_mfma_f32_16x16x32_f16(a[rt], bw[ct], acc[rt][ct], 0, 0, 0);
  }

  const int bidx = m0 >> 11, sbase = m0 & 2047;
  if (z != 2) {
    #pragma unroll
    for (int rt = 0; rt < 2; ++rt)
      #pragma unroll
      for (int r = 0; r < 4; ++r) {
        int s = sbase + rt * 16 + g * 4 + r;
        _Float16* orow = outp + ((size_t)((bidx * 8 + h) * 2048 + s) << 6);
        #pragma unroll
        for (int ct = 0; ct < 4; ++ct)
          orow[ct * 16 + li] = (_Float16)acc[rt][ct][r];
      }
  } else {
    // transpose 32s x 64d tile through swizzled LDS, emit Vt rows
    char* lt = lt_all + wave * (64 * 144);
    #pragma unroll
    for (int rt = 0; rt < 2; ++rt)
      #pragma unroll
      for (int ct = 0; ct < 4; ++ct)
        #pragma unroll
        for (int r = 0; r < 4; ++r) {
          int d = ct * 16 + li, sl = rt * 16 + g * 4 + r;
          *(_Float16*)(lt + d * 144 + ((sl * 2) ^ ((d & 7) << 4))) = (_Float16)acc[rt][ct][r];
        }
    __syncthreads();
    int d = lane;  // 0..63
    _Float16* vrow = outp + (size_t)((bidx * 8 + h) * 64 + d) * 2048 + sbase;
    #pragma unroll
    for (int c = 0; c < 4; ++c) {
      half8 vv = *(half8*)(lt + d * 144 + ((c * 16) ^ ((d & 7) << 4)));
      *(half8*)(vrow + c * 8) = vv;
    }
  }
}

// ---------------- kernel 4: fused flash attention + T5 relative bias ---------
// grid (S/64, B*H); block 128 (2 waves x 32 q-rows) -> 1024 blocks, 4/CU.
__global__ __launch_bounds__(128) void attn_kernel(const _Float16* __restrict__ Qp,
                                                   const _Float16* __restrict__ Kp,
                                                   const _Float16* __restrict__ Vt,
                                                   const float* __restrict__ kmask,
                                                   const float* __restrict__ rel_emb,
                                                   float* __restrict__ outp) {
  __shared__ float bias_tab[4096];
  __shared__ __align__(16) char pb_all[2 * 4096];
  const int bh = blockIdx.y, b = bh >> 3, h = bh & 7;
  const int wave = threadIdx.x >> 6, lane = threadIdx.x & 63;
  const int g = lane >> 4, li = lane & 15;
  const int qw = blockIdx.x * 64 + wave * 32;

  // T5 bucket bias table for this head; exact integer thresholds (no logf).
  for (int idx = (int)threadIdx.x; idx < 4095; idx += 128) {
    int rel = idx - 2047;
    int ret = rel > 0 ? 16 : 0;
    int rp = rel < 0 ? -rel : rel;
    int bb;
    if (rp < 8) bb = rp;
    else {
      int t = (rp >= 12) + (rp >= 16) + (rp >= 23) + (rp >= 32) +
              (rp >= 46) + (rp >= 64) + (rp >= 91);
      bb = 8 + t;
    }
    bias_tab[idx] = rel_emb[(ret + bb) * 8 + h];
  }
  const float bias_far_neg = rel_emb[15 * 8 + h];   // rel <= -91
  const float bias_far_pos = rel_emb[31 * 8 + h];   // rel >=  91

  const _Float16* Qb = Qp + (size_t)bh * (2048 * 64);
  const _Float16* Kb = Kp + (size_t)bh * (2048 * 64);
  const _Float16* Vb = Vt + (size_t)bh * (64 * 2048);
  const float* mkb = kmask + b * 2048;

  half8 qa[2][2];
  #pragma unroll
  for (int rt = 0; rt < 2; ++rt)
    #pragma unroll
    for (int kc = 0; kc < 2; ++kc)
      qa[rt][kc] = *(const half8*)(Qb + (size_t)(qw + rt * 16 + li) * 64 + kc * 32 + g * 8);

  f32x4 o[2][4];
  float mrow[2][4], lrow[2][4];
  #pragma unroll
  for (int rt = 0; rt < 2; ++rt) {
    #pragma unroll
    for (int ct = 0; ct < 4; ++ct) o[rt][ct] = (f32x4){0.f, 0.f, 0.f, 0.f};
    #pragma unroll
    for (int r = 0; r < 4; ++r) { mrow[rt][r] = -1e30f; lrow[rt][r] = 0.f; }
  }
  char* pb = pb_all + wave * 4096;

  __syncthreads();   // bias table ready

  for (int j0 = 0; j0 < 2048; j0 += 64) {
    // ---- K fragments (direct 16B loads, L2-resident) ----
    half8 kb[4][2];
    #pragma unroll
    for (int jt = 0; jt < 4; ++jt)
      #pragma unroll
      for (int kc = 0; kc < 2; ++kc)
        kb[jt][kc] = *(const half8*)(Kb + (size_t)(j0 + jt * 16 + li) * 64 + kc * 32 + g * 8);
    float mterm[4];
    #pragma unroll
    for (int jt = 0; jt < 4; ++jt)
      mterm[jt] = (1.0f - mkb[j0 + jt * 16 + li]) * -10000.0f;

    // ---- scores = Q K^T ----
    f32x4 sc[2][4];
    __builtin_amdgcn_s_setprio(1);
    #pragma unroll
    for (int rt = 0; rt < 2; ++rt)
      #pragma unroll
      for (int jt = 0; jt < 4; ++jt) {
        f32x4 z = (f32x4){0.f, 0.f, 0.f, 0.f};
        z = __builtin_amdgcn_mfma_f32_16x16x32_f16(qa[rt][0], kb[jt][0], z, 0, 0, 0);
        sc[rt][jt] = __builtin_amdgcn_mfma_f32_16x16x32_f16(qa[rt][1], kb[jt][1], z, 0, 0, 0);
      }
    __builtin_amdgcn_s_setprio(0);

    // ---- bias + mask (wave-uniform far-tile fast path) ----
    #pragma unroll
    for (int rt = 0; rt < 2; ++rt)
      #pragma unroll
      for (int jt = 0; jt < 4; ++jt) {
        int jlo = j0 + jt * 16, qlo = qw + rt * 16;
        if (jlo - (qlo + 15) >= 91) {
          #pragma unroll
          for (int r = 0; r < 4; ++r) sc[rt][jt][r] += bias_far_pos + mterm[jt];
        } else if ((jlo + 15) - qlo <= -91) {
          #pragma unroll
          for (int r = 0; r < 4; ++r) sc[rt][jt][r] += bias_far_neg + mterm[jt];
        } else {
          #pragma unroll
          for (int r = 0; r < 4; ++r)
            sc[rt][jt][r] += bias_tab[(jlo + li) - (qlo + g * 4 + r) + 2047] + mterm[jt];
        }
      }

    // ---- deferred-max online softmax (T13): skip butterfly+rescale unless
    //      some row's local max exceeds running max by >8 (P <= e^8, fp16-safe)
    float lmax[2][4];
    int need = 0;
    #pragma unroll
    for (int rt = 0; rt < 2; ++rt)
      #pragma unroll
      for (int r = 0; r < 4; ++r) {
        lmax[rt][r] = fmaxf(fmaxf(sc[rt][0][r], sc[rt][1][r]),
                            fmaxf(sc[rt][2][r], sc[rt][3][r]));
        need |= (lmax[rt][r] - mrow[rt][r] > 8.0f);
      }
    if (__any(need)) {
      #pragma unroll
      for (int rt = 0; rt < 2; ++rt) {
        #pragma unroll
        for (int r = 0; r < 4; ++r) {
          float t = lmax[rt][r];
          t = fmaxf(t, __shfl_xor(t, 1));
          t = fmaxf(t, __shfl_xor(t, 2));
          t = fmaxf(t, __shfl_xor(t, 4));
          t = fmaxf(t, __shfl_xor(t, 8));
          float mnew = fmaxf(mrow[rt][r], t);
          float scal = exp2f((mrow[rt][r] - mnew) * LOG2E);
          mrow[rt][r] = mnew;
          lrow[rt][r] *= scal;
          #pragma unroll
          for (int ct = 0; ct < 4; ++ct) o[rt][ct][r] *= scal;
        }
      }
    }
    #pragma unroll
    for (int rt = 0; rt < 2; ++rt)
      #pragma unroll
      for (int r = 0; r < 4; ++r) {
        float ps = 0.f;
        #pragma unroll
        for (int jt = 0; jt < 4; ++jt) {
          float p = exp2f((sc[rt][jt][r] - mrow[rt][r]) * LOG2E);
          sc[rt][jt][r] = p;
          ps += p;
        }
        lrow[rt][r] += ps;   // per-lane partial; reduced at end
      }

    // ---- P -> fp16 -> wave-private swizzled LDS (C-layout -> A-layout) ----
    #pragma unroll
    for (int rt = 0; rt < 2; ++rt)
      #pragma unroll
      for (int jt = 0; jt < 4; ++jt)
        #pragma unroll
        for (int r = 0; r < 4; ++r) {
          int row = rt * 16 + g * 4 + r, col = jt * 16 + li;
          *(_Float16*)(pb + row * 128 + ((col * 2) ^ ((row & 7) << 4))) =
              (_Float16)sc[rt][jt][r];
        }
    half8 pa[2][2];
    #pragma unroll
    for (int rt = 0; rt < 2; ++rt)
      #pragma unroll
      for (int jc = 0; jc < 2; ++jc) {
        int row = rt * 16 + li;
        pa[rt][jc] = *(half8*)(pb + row * 128 + (((jc * 32 + g * 8) * 2) ^ ((row & 7) << 4)));
      }

    // ---- O += P V  (V pre-transposed: direct contiguous 16B B-frags) ----
    __builtin_amdgcn_s_setprio(1);
    #pragma unroll
    for (int dct = 0; dct < 4; ++dct) {
      half8 vb0 = *(const half8*)(Vb + (size_t)(dct * 16 + li) * 2048 + j0 + g * 8);
      half8 vb1 = *(const half8*)(Vb + (size_t)(dct * 16 + li) * 2048 + j0 + 32 + g * 8);
      #pragma unroll
      for (int rt = 0; rt < 2; ++rt) {
        o[rt][dct] = __builtin_amdgcn_mfma_f32_16x16x32_f16(pa[rt][0], vb0, o[rt][dct], 0, 0, 0);
        o[rt][dct] = __builtin_amdgcn_mfma_f32_16x16x32_f16(pa[rt][1], vb1, o[rt][dct], 0, 0, 0);
      }
    }
    __builtin_amdgcn_s_setprio(0);
  }

  // ---- epilogue: reduce l, divide, store f32 ----
  #pragma unroll
  for (int rt = 0; rt < 2; ++rt)
    #pragma unroll
    for (int r = 0; r < 4; ++r) {
      float t = lrow[rt][r];
      t += __shfl_xor(t, 1);
      t += __shfl_xor(t, 2);
      t += __shfl_xor(t, 4);
      t += __shfl_xor(t, 8);
      float inv = 1.0f / t;
      int qrow = qw + rt * 16 + g * 4 + r;
      float* orow = outp + ((size_t)b * 2048 + qrow) * 512 + h * 64;
      #pragma unroll
      for (int ct = 0; ct < 4; ++ct)
        orow[ct * 16 + li] = o[rt][ct][r] * inv;
    }
}

extern "C" void kernel_launch(void* const* d_in, const int* in_sizes, int n_in,
                              void* d_out, int out_size, void* d_ws, size_t ws_size,
                              hipStream_t stream) {
  const float* query = (const float*)d_in[0];
  const float* key   = (const float*)d_in[1];
  const float* value = (const float*)d_in[2];
  const float* kmask = (const float*)d_in[3];
  const float* Wq    = (const float*)d_in[4];
  const float* Wk    = (const float*)d_in[5];
  const float* Wv    = (const float*)d_in[6];
  const float* rel   = (const float*)d_in[7];

  char* ws = (char*)d_ws;
  const size_t SZB = 8192ull * 512 * 2;   // one f16 tensor: 8 MiB
  const size_t WB  = 512ull * 512 * 2;
  _Float16* xq  = (_Float16*)(ws);
  _Float16* xk  = (_Float16*)(ws + SZB);
  _Float16* xv  = (_Float16*)(ws + 2 * SZB);
  _Float16* wtq = (_Float16*)(ws + 3 * SZB);
  _Float16* wtk = (_Float16*)(ws + 3 * SZB + WB);
  _Float16* wtv = (_Float16*)(ws + 3 * SZB + 2 * WB);
  _Float16* qp  = (_Float16*)(ws + 3 * SZB + 3 * WB);
  _Float16* kp  = (_Float16*)(ws + 4 * SZB + 3 * WB);
  _Float16* vt  = (_Float16*)(ws + 5 * SZB + 3 * WB);

  cvt_h_kernel<<<dim3(2048, 3), dim3(256), 0, stream>>>(query, key, value, xq, xk, xv);
  wtrans_kernel<<<dim3(16, 16, 3), dim3(256), 0, stream>>>(Wq, Wk, Wv, wtq, wtk, wtv);
  proj_kernel<<<dim3(64, 8, 3), dim3(256), 0, stream>>>(xq, xk, xv, wtq, wtk, wtv, qp, kp, vt);
  attn_kernel<<<dim3(32, 32), dim3(128), 0, stream>>>(qp, kp, vt, kmask, rel, (float*)d_out);
}